// Round 15
// baseline (31.956 us; speedup 1.0000x reference)
//
#include <hip/hip_runtime.h>
#include <hip/hip_bf16.h>

// LBS skinning as bf16 MFMA GEMM (swapped operands), persistent single
// kernel. R15: weight gather -> coalesced per-wave stream. Per tile each
// wave loads its 32 weight rows (6656 B) as 7 contiguous float4 loads
// issued ONE TILE EARLY (fly under k-loop+epilogue), ds_writes them to a
// wave-private LDS stage, and reads per-lane float2s from LDS (2-way bank
// alias = free). Epilogue transpose slices ALIAS the W-stage (W consumed
// to regs before slices written; slices dead before next stage_w).
// LDS 43008 + 4*6656 = 69632 -> 2 blocks/CU. No per-tile block barriers;
// wave-level lgkm RAW/WAR fence discipline (R10).
// V=100000, N=96, K=208 (padded to 224 = 7 steps of 32)

typedef __attribute__((ext_vector_type(8))) short bf16x8;
typedef __attribute__((ext_vector_type(4))) float f32x4;

constexpr int J      = 52;
constexpr int NT     = 6;                  // 6 n-tiles of 16 -> N=96
constexpr int WAVES  = 4;
constexpr int MT     = 2;                  // m-tiles (16 verts) per wave
constexpr int VPW    = MT * 16;            // 32 verts per wave
constexpr int VPB    = WAVES * VPW;        // 128 verts per block
constexpr int KSTEPS = 7;
constexpr int GMAX   = 512;                // persistent grid (2 blocks/CU)

constexpr int BP_B   = KSTEPS * NT * 64 * 16;  // 43008 B packed-A layout
constexpr int SPAD   = 100;                // epilogue dwords per b (96 padded)
constexpr int SL_B   = 16 * SPAD * 4;      // 6400 B slice (aliases W stage)
constexpr int WS_B   = VPW * J * 4;        // 6656 B per-wave W stage
constexpr int WCH    = VPW * J / 4;        // 416 float4 chunks per wave
constexpr int NF4    = 32 * J * 4;         // 6656 float4 in xf (= 26*256)

__device__ __forceinline__ unsigned pk2(float a, float b) {
    __hip_bfloat162 h = __float22bfloat162_rn(make_float2(a, b));
    return *reinterpret_cast<unsigned*>(&h);
}

__global__ __launch_bounds__(256, 2) void skin_persist(
    const float* __restrict__ verts,
    const float* __restrict__ weights,
    const float* __restrict__ xf,
    float* __restrict__ out,
    int V, int ntiles, int gsize)
{
    __shared__ __align__(16) char sBp[BP_B];          // packed A (read-only)
    __shared__ __align__(16) char sWS[WAVES][WS_B];   // W stage / epi slices

    const int tid  = threadIdx.x;
    const int lane = tid & 63;
    const int wid  = tid >> 6;
    const int lgrp = lane >> 4;
    const int lrow = lane & 15;
    char* const sW = sWS[wid];

    int tv = blockIdx.x;               // first tile

    // ---- issue tile-1 W stream + verts (fly during the pack) ----
    f32x4 wreg[7];
    {
        const size_t base = (size_t)(tv * VPB + wid * VPW) * 13;  // f4 units
        const size_t lim  = (size_t)V * 13 - 1;
#pragma unroll
        for (int it = 0; it < 7; ++it) {
            const int c = it * 64 + lane;
            size_t fidx = base + (c < WCH ? c : WCH - 1);
            if (fidx > lim) fidx = lim;        // clamped rows never stored
            wreg[it] = *(const f32x4*)(weights + fidx * 4);
        }
    }
    float hx[MT], hy[MT], hz[MT];
#pragma unroll
    for (int mt = 0; mt < MT; ++mt) {
        const int v   = tv * VPB + wid * VPW + mt * 16 + lrow;
        const int vcl = (v < V) ? v : (V - 1);
        hx[mt] = verts[3 * (size_t)vcl + 0];
        hy[mt] = verts[3 * (size_t)vcl + 1];
        hz[mt] = verts[3 * (size_t)vcl + 2];
    }

    // ---- in-block pack: coalesced xf stream -> LDS fragment layout ----
    {
        const float4* __restrict__ xf4 = reinterpret_cast<const float4*>(xf);
        for (int it = 0; it < NF4 / 256; ++it) {
            const int g = it * 256 + tid;
            const float4 m = xf4[g];           // fully coalesced
            const int b   = g / 208;           // 208 = J*4 f4 per batch
            const int rem = g - b * 208;
            const int j = rem >> 2;
            const int i = rem & 3;
            if (i < 3) {
                const int n    = 3 * b + i;    // < 96
                const int slot = ((j >> 3) * NT + (n >> 4)) * 64
                               + ((j >> 1) & 3) * 16 + (n & 15);
                uint2 d;
                d.x = pk2(m.x, m.y);
                d.y = pk2(m.z, m.w);
                *(uint2*)(sBp + slot * 16 + (j & 1) * 8) = d;
            }
        }
        for (int z = tid; z < NT * 32; z += 256) {   // zero s=6 lgrp 2/3
            const int t = z >> 5, l = z & 31;
            const int slot = (6 * NT + t) * 64 + 32 + l;
            *(f32x4*)(sBp + slot * 16) = f32x4{0.f, 0.f, 0.f, 0.f};
        }
    }
    // stage tile-1 W (vmcnt auto-wait on wreg)
#pragma unroll
    for (int it = 0; it < 7; ++it) {
        const int c = it * 64 + lane;
        if (c < WCH) *(f32x4*)(sW + c * 16) = wreg[it];
    }
    __syncthreads();   // the only block barrier; sBp read-only afterwards

    // ---- persistent tile loop (all wave-private from here) ----
    for (;;) {
        const int tvn = tv + gsize;

        // issue NEXT tile's W stream immediately (no LDS dependency)
        if (tvn < ntiles) {
            const size_t base = (size_t)(tvn * VPB + wid * VPW) * 13;
            const size_t lim  = (size_t)V * 13 - 1;
#pragma unroll
            for (int it = 0; it < 7; ++it) {
                const int c = it * 64 + lane;
                size_t fidx = base + (c < WCH ? c : WCH - 1);
                if (fidx > lim) fidx = lim;
                wreg[it] = *(const f32x4*)(weights + fidx * 4);
            }
        }

        // fence: sW(tv) ds_writes complete (lgkm is out-of-order)
        asm volatile("s_waitcnt lgkmcnt(0)" ::: "memory");
        __builtin_amdgcn_sched_barrier(0);

        // per-lane wv from LDS (2-way bank alias at worst)
        float2 wv[MT][KSTEPS];
#pragma unroll
        for (int mt = 0; mt < MT; ++mt) {
            const char* rb = sW + ((mt * 16 + lrow) * J) * 4;
#pragma unroll
            for (int s = 0; s < KSTEPS; ++s) {
                const int j0 = s * 8 + lgrp * 2;
                wv[mt][s] = (j0 < J) ? *(const float2*)(rb + j0 * 4)
                                     : float2{0.f, 0.f};
            }
        }

        // ---- k-loop: pure LDS + VALU + MFMA ----
        f32x4 acc[MT][NT];
#pragma unroll
        for (int mt = 0; mt < MT; ++mt)
#pragma unroll
            for (int t = 0; t < NT; ++t)
                acc[mt][t] = f32x4{0.f, 0.f, 0.f, 0.f};

#pragma unroll
        for (int s = 0; s < KSTEPS; ++s) {
            bf16x8 frag[NT];
#pragma unroll
            for (int t = 0; t < NT; ++t)
                frag[t] = *(const bf16x8*)(sBp + ((s * NT + t) * 64 + lane) * 16);
#pragma unroll
            for (int mt = 0; mt < MT; ++mt) {
                const float w0 = wv[mt][s].x, w1 = wv[mt][s].y;
                union { bf16x8 v; unsigned w[4]; } xf8;
                xf8.w[0] = pk2(w0 * hx[mt], w0 * hy[mt]);
                xf8.w[1] = pk2(w0 * hz[mt], w0);
                xf8.w[2] = pk2(w1 * hx[mt], w1 * hy[mt]);
                xf8.w[3] = pk2(w1 * hz[mt], w1);
#pragma unroll
                for (int t = 0; t < NT; ++t)
                    acc[mt][t] = __builtin_amdgcn_mfma_f32_16x16x32_bf16(
                        frag[t], xf8.v, acc[mt][t], 0, 0, 0);
            }
        }

        // capture current-tile params; prefetch next verts
        const int v0w = tv * VPB + wid * VPW;
        const long long validf = ((long long)V - v0w) * 3;
        if (tvn < ntiles) {
#pragma unroll
            for (int mt = 0; mt < MT; ++mt) {
                const int v   = tvn * VPB + wid * VPW + mt * 16 + lrow;
                const int vcl = (v < V) ? v : (V - 1);
                hx[mt] = verts[3 * (size_t)vcl + 0];
                hy[mt] = verts[3 * (size_t)vcl + 1];
                hz[mt] = verts[3 * (size_t)vcl + 2];
            }
        }

        // ---- epilogue: slices alias sW (W consumed to regs above) ----
        char* const sl = sW;
#pragma unroll
        for (int h = 0; h < 2; ++h) {
#pragma unroll
            for (int mt = 0; mt < MT; ++mt) {
                const int vloc = mt * 16 + lrow;
#pragma unroll
                for (int tt = 0; tt < 3; ++tt) {
                    const int t = 3 * h + tt;
#pragma unroll
                    for (int r = 0; r < 4; ++r) {
                        const int n  = 16 * t + lgrp * 4 + r;
                        const int b  = n / 3;
                        const int i  = n - 3 * b;
                        const int fl = (b - 16 * h) * SPAD + vloc * 3 + i;
                        *(float*)(sl + fl * 4) = acc[mt][t][r];
                    }
                }
            }
            // RAW fence: ds_writes complete before reads
            asm volatile("s_waitcnt lgkmcnt(0)" ::: "memory");
            __builtin_amdgcn_sched_barrier(0);

            f32x4 vals[6];
#pragma unroll
            for (int q = 0; q < 6; ++q) {
                const int f  = q * 64 + lane;
                const int bl = f / 24;
                const int rr = f - bl * 24;
                vals[q] = *(const f32x4*)(sl + bl * (SPAD * 4) + rr * 16);
            }
            // WAR fence: reads in regs before next writes (slices or stage_w)
            asm volatile("s_waitcnt lgkmcnt(0)" ::: "memory");
            __builtin_amdgcn_sched_barrier(0);

#pragma unroll
            for (int q = 0; q < 6; ++q) {
                const int f  = q * 64 + lane;
                const int bl = f / 24;
                const int rr = f - bl * 24;
                float* dst = out + (size_t)(16 * h + bl) * (size_t)V * 3
                                 + (size_t)v0w * 3 + rr * 4;
                if ((long long)(rr + 1) * 4 <= validf) {
                    *(float4*)dst = *(const float4*)&vals[q];
                } else if ((long long)rr * 4 < validf) {   // partial tail
#pragma unroll
                    for (int e = 0; e < 4; ++e)
                        if ((long long)(rr * 4 + e) < validf) dst[e] = vals[q][e];
                }
            }
        }

        if (tvn >= ntiles) break;

        // stage next tile's W into sW (slices dead; WAR fence above ran;
        // compiler inserts vmcnt wait on wreg arrivals)
#pragma unroll
        for (int it = 0; it < 7; ++it) {
            const int c = it * 64 + lane;
            if (c < WCH) *(f32x4*)(sW + c * 16) = wreg[it];
        }
        tv = tvn;
    }
}

extern "C" void kernel_launch(void* const* d_in, const int* in_sizes, int n_in,
                              void* d_out, int out_size, void* d_ws, size_t ws_size,
                              hipStream_t stream)
{
    const float* verts   = (const float*)d_in[0];
    const float* weights = (const float*)d_in[1];
    const float* xf      = (const float*)d_in[2];
    float* out = (float*)d_out;

    const int V = in_sizes[0] / 3;               // 100000
    const int ntiles = (V + VPB - 1) / VPB;      // 782
    const int G = ntiles < GMAX ? ntiles : GMAX; // 512 persistent blocks

    skin_persist<<<G, 256, 0, stream>>>(verts, weights, xf, out, V, ntiles, G);
}

// Round 16
// 23.827 us; speedup vs baseline: 1.3412x; 1.3412x over previous
//
#include <hip/hip_runtime.h>
#include <hip/hip_bf16.h>

// LBS skinning as bf16 MFMA GEMM (swapped operands), two-phase:
//   Phase 1 (pack_A): compact A[k=4j+c][n=3b+i] = M[b,j,i,c] in MFMA
//     fragment lane order in d_ws (39952 B written; 40960 staged).
//   Phase 2 (skin_mfma): D[n][v] = sum_k A[k,n] * X[v,k],
//     X[v,4j+c] = w[v,j]*h_v[c], h=(x,y,z,1).
//   LDS = exactly 40960 B -> 4 blocks/CU (160 KB exact) and 782 blocks
//   all resident in ONE generation (1024 slots). Epilogue transposes
//   through wave-private 6-KB slices REUSING sBp (dead after k-loop);
//   lgkm out-of-order completion handled by explicit RAW/WAR fences
//   (R9 bug / R10 fix).
// [R16: byte-identical revert to R11 = best measured 23.84 us. R12-R15
//  falsified: stage pipelining, epilogue pad, fused pack, persistence,
//  coalesced W-staging -- all flat or regressions. Steady-state body is
//  at the HBM floor (R13 diag: 8.6 us marginal pass); residual is fixed
//  launch/ramp cost, not kernel structure.]
// V=100000, N=96, K=208 (padded to 224 = 7 steps of 32)

typedef __attribute__((ext_vector_type(8))) short bf16x8;
typedef __attribute__((ext_vector_type(4))) float f32x4;

constexpr int J      = 52;
constexpr int KSTEPS = 7;
constexpr int NT     = 6;                  // 6 n-tiles of 16 -> N=96
constexpr int WAVES  = 4;
constexpr int MT     = 2;                  // m-tiles (16 verts) per wave
constexpr int VPW    = MT * 16;            // 32 verts per wave
constexpr int VPB    = WAVES * VPW;        // 128 verts per block

constexpr int SLOTS_FULL = 6 * NT * 64;    // 2304 slots, s = 0..5
constexpr int SLOTS_S6   = NT * 32;        // 192 slots, s = 6 (lgrp 0/1 only)
constexpr int ZSLOT      = SLOTS_FULL + SLOTS_S6;  // 2496: broadcast zero slot
constexpr int NSLOT      = ZSLOT + 1;      // 2497 slots written by pack_A
constexpr int S6_BASE_B  = SLOTS_FULL * 16;        // 36864
constexpr int Z_B        = ZSLOT * 16;             // 39936
constexpr int LDS_B      = 40960;          // 4 blocks/CU exactly
constexpr int SL_B       = 16 * VPW * 3 * 4;       // 6144 B epilogue slice

typedef const __attribute__((address_space(1))) char* gas1_t;
typedef __attribute__((address_space(3))) char* las3_t;

__device__ __forceinline__ unsigned pk2(float a, float b) {
    __hip_bfloat162 h = __float22bfloat162_rn(make_float2(a, b));
    return *reinterpret_cast<unsigned*>(&h);
}

__global__ __launch_bounds__(256) void pack_A(
    const float* __restrict__ xf,
    bf16x8* __restrict__ Bp)
{
    const int slot = blockIdx.x * 256 + threadIdx.x;
    if (slot >= NSLOT) return;

    if (slot == ZSLOT) {                       // broadcast zero slot
        union { bf16x8 v; unsigned w[4]; } z;
        z.w[0] = z.w[1] = z.w[2] = z.w[3] = 0u;
        Bp[slot] = z.v;
        return;
    }

    int s, t, l;
    if (slot < SLOTS_FULL) {
        s = slot / (NT * 64);
        const int rem = slot - s * (NT * 64);
        t = rem >> 6;
        l = rem & 63;
    } else {
        s = 6;
        const int rem = slot - SLOTS_FULL;
        t = rem >> 5;
        l = rem & 31;                          // lgrp 0/1 only
    }
    const int lgrp = l >> 4;
    const int lrow = l & 15;
    const int n = t * 16 + lrow;               // n = 3b + i, < 96
    const int b = n / 3;
    const int i = n - 3 * b;
    const int j0 = s * 8 + lgrp * 2;           // <= 50 for all stored slots

    const float4* __restrict__ xf4 = reinterpret_cast<const float4*>(xf);
    const float4 m0 = xf4[(b * J + j0) * 4 + i];
    const float4 m1 = xf4[(b * J + j0 + 1) * 4 + i];
    union { bf16x8 v; unsigned w[4]; } r;
    r.w[0] = pk2(m0.x, m0.y); r.w[1] = pk2(m0.z, m0.w);
    r.w[2] = pk2(m1.x, m1.y); r.w[3] = pk2(m1.z, m1.w);
    Bp[slot] = r.v;
}

__global__ __launch_bounds__(256, 4) void skin_mfma(
    const float* __restrict__ verts,
    const float* __restrict__ weights,
    const bf16x8* __restrict__ Bp,
    float* __restrict__ out,
    int V)
{
    __shared__ __align__(16) char sBp[LDS_B];  // 40960 B -> 4 blocks/CU exact

    const int tid  = threadIdx.x;
    const int lane = tid & 63;
    const int wid  = tid >> 6;
    const int lgrp = lane >> 4;
    const int lrow = lane & 15;
    const int v0   = blockIdx.x * VPB;
    const int v0w  = v0 + wid * VPW;           // this wave's base vertex

    // ---- issue A-stage: 40 KB linear, wave-striped 1KB chunks ----
    {
        const char* g = (const char*)Bp;
        for (int p = wid; p < LDS_B / 1024; p += WAVES) {
            __builtin_amdgcn_global_load_lds(
                (gas1_t)(g + p * 1024 + lane * 16),
                (las3_t)(sBp + p * 1024), 16, 0, 0);
        }
    }

    // ---- reg loads in the stage's shadow (verts + weights) ----
    float hx[MT], hy[MT], hz[MT];
    float2 wv[MT][KSTEPS];
#pragma unroll
    for (int mt = 0; mt < MT; ++mt) {
        const int v   = v0w + mt * 16 + lrow;
        const int vcl = (v < V) ? v : (V - 1);   // clamped lanes never stored
        hx[mt] = verts[3 * (size_t)vcl + 0];
        hy[mt] = verts[3 * (size_t)vcl + 1];
        hz[mt] = verts[3 * (size_t)vcl + 2];
        const float* wr = weights + (size_t)vcl * J;
#pragma unroll
        for (int s = 0; s < KSTEPS; ++s) {
            const int j0 = s * 8 + lgrp * 2;     // only s=6, lgrp>=2 exceeds J
            wv[mt][s] = (j0 < J) ? *(const float2*)(wr + j0) : float2{0.f, 0.f};
        }
    }

    __syncthreads();   // A staged

    // ---- k-loop: pure LDS + VALU + MFMA ----
    f32x4 acc[MT][NT];
#pragma unroll
    for (int mt = 0; mt < MT; ++mt)
#pragma unroll
        for (int t = 0; t < NT; ++t)
            acc[mt][t] = f32x4{0.f, 0.f, 0.f, 0.f};

#pragma unroll
    for (int s = 0; s < KSTEPS; ++s) {
        bf16x8 frag[NT];
#pragma unroll
        for (int t = 0; t < NT; ++t) {
            if (s < 6) {
                frag[t] = *(const bf16x8*)(sBp + ((s * NT + t) * 64 + lane) * 16);
            } else {
                const char* p = (lane < 32)
                    ? (sBp + S6_BASE_B + (t * 32 + lane) * 16)
                    : (sBp + Z_B);               // 32-lane broadcast of zeros
                frag[t] = *(const bf16x8*)p;
            }
        }
#pragma unroll
        for (int mt = 0; mt < MT; ++mt) {
            const float w0 = wv[mt][s].x, w1 = wv[mt][s].y;
            union { bf16x8 v; unsigned w[4]; } xf8;
            xf8.w[0] = pk2(w0 * hx[mt], w0 * hy[mt]);
            xf8.w[1] = pk2(w0 * hz[mt], w0);
            xf8.w[2] = pk2(w1 * hx[mt], w1 * hy[mt]);
            xf8.w[3] = pk2(w1 * hz[mt], w1);
#pragma unroll
            for (int t = 0; t < NT; ++t) {
                // SWAPPED: A = matrix (rows n), B = X (cols v)
                acc[mt][t] = __builtin_amdgcn_mfma_f32_16x16x32_bf16(
                    frag[t], xf8.v, acc[mt][t], 0, 0, 0);
            }
        }
    }

    __syncthreads();   // all frag reads done -> sBp reusable as epilogue slices

    // ---- epilogue: wave-private slices inside sBp, contiguous f4 stores ----
    // Lane holds D[n = 16t + lgrp*4 + r][v = v0w + mt*16 + lrow].
    // Half h: t in [3h,3h+3) -> b in [16h,16h+16) exact.
    // Slice layout: ((b-16h)*VPW + vloc)*3 + i, vloc = mt*16+lrow.
    char* const sl = sBp + wid * SL_B;
    const long long validf = ((long long)V - v0w) * 3;  // valid floats per b-run
#pragma unroll
    for (int h = 0; h < 2; ++h) {
#pragma unroll
        for (int mt = 0; mt < MT; ++mt) {
            const int vloc = mt * 16 + lrow;
#pragma unroll
            for (int tt = 0; tt < 3; ++tt) {
                const int t = 3 * h + tt;
#pragma unroll
                for (int r = 0; r < 4; ++r) {
                    const int n  = 16 * t + lgrp * 4 + r;
                    const int b  = n / 3;
                    const int i  = n - 3 * b;
                    const int fl = ((b - 16 * h) * VPW + vloc) * 3 + i;
                    *(float*)(sl + fl * 4) = acc[mt][t][r];
                }
            }
        }
        // RAW fence: ds_writes complete before reads (lgkm is out-of-order)
        asm volatile("s_waitcnt lgkmcnt(0)" ::: "memory");
        __builtin_amdgcn_sched_barrier(0);

        f32x4 vals[6];
#pragma unroll
        for (int q = 0; q < 6; ++q) {
            const int f = q * 64 + lane;       // float4 index in slice, 0..383
            vals[q] = *(const f32x4*)(sl + f * 16);
        }
        // WAR fence: reads complete (in regs) before next half's writes
        asm volatile("s_waitcnt lgkmcnt(0)" ::: "memory");
        __builtin_amdgcn_sched_barrier(0);

#pragma unroll
        for (int q = 0; q < 6; ++q) {
            const int f  = q * 64 + lane;
            const int bl = f / 24;             // local b, 0..15
            const int rr = f - bl * 24;        // float4 within the 384-B b-run
            float* dst = out + (size_t)(16 * h + bl) * (size_t)V * 3
                             + (size_t)v0w * 3 + rr * 4;
            if ((long long)(rr + 1) * 4 <= validf) {
                *(float4*)dst = *(const float4*)&vals[q];
            } else if ((long long)rr * 4 < validf) {   // generic partial tail
#pragma unroll
                for (int e = 0; e < 4; ++e)
                    if ((long long)(rr * 4 + e) < validf) dst[e] = vals[q][e];
            }
        }
    }
}

extern "C" void kernel_launch(void* const* d_in, const int* in_sizes, int n_in,
                              void* d_out, int out_size, void* d_ws, size_t ws_size,
                              hipStream_t stream)
{
    const float* verts   = (const float*)d_in[0];
    const float* weights = (const float*)d_in[1];
    const float* xf      = (const float*)d_in[2];
    float* out = (float*)d_out;

    const int V = in_sizes[0] / 3;   // 100000
    bf16x8* Bp = (bf16x8*)d_ws;      // 39952 B written; 40960 B staged

    pack_A<<<(NSLOT + 255) / 256, 256, 0, stream>>>(xf, Bp);
    const int nblocks = (V + VPB - 1) / VPB;
    skin_mfma<<<nblocks, 256, 0, stream>>>(verts, weights, Bp, out, V);
}